// Round 2
// baseline (415.868 us; speedup 1.0000x reference)
//
#include <hip/hip_runtime.h>
#include <hip/hip_cooperative_groups.h>

namespace cg = cooperative_groups;

// DigitCaps, fp32 in / fp32 out:
//   u [16,1152,8], W [10,1152,16,8], Bp [10,1,1152], out [16,10,16]
// Exact algebra: A_sum[b,d,m] = dot(T[b,d,:], U_hat[b,d,m,:])/sqrt8,
//   T = sum_n U_hat;  C = softmax_d;  S = sum_n (Bp+C)*U_hat;  squash(S).
// R15: single cooperative kernel. R14's reduce-unroll was a no-op (compiler
// had already unrolled) -> the ~83 us is pipeline structure: 4 dependent
// launches + W staged twice. Fused: stage W once, keep votes uh[2][10] in
// registers across grid.sync(), 3 syncs replace 3 kernel boundaries.
// All FP orders identical to the 4-kernel version (bitwise-same output).
constexpr int BN = 16, NN = 1152, DP = 8, ND = 10, DD = 16;
constexpr int NCH = 2;                   // n's per phase block
constexpr int NBLK = NN / NCH;           // 576 blocks
constexpr int CELLS = BN * ND * DD;      // 2560; cell = d*256 + b*16 + j
constexpr int RL = 16;                   // reduction lanes per cell
constexpr int RK = NBLK / RL;            // 36 partials per reduction lane
constexpr int WCH = NCH * ND;            // 20 staged W chunks (512 B each)
constexpr int RBLK = CELLS / RL;         // 160 reduce blocks

// ================== fused cooperative kernel ==================
__global__ __launch_bounds__(256, 3) void caps_fused(
    const float* __restrict__ u, const float* __restrict__ W,
    const float* __restrict__ Bp, float* __restrict__ Tp,
    float* __restrict__ T, float* __restrict__ Sp,
    float* __restrict__ out)
{
    cg::grid_group grid = cg::this_grid();
    __shared__ float Wl[WCH * 128];      // 10 KB, persists phase A only
    __shared__ float ul[BN * NCH * DP];  // 1 KB
    __shared__ float red[256];           // 1 KB reduce scratch

    const int t = threadIdx.x;
    const int blk = blockIdx.x;
    const int n0 = blk * NCH;
    constexpr float RS8 = 0.35355339059327373f;    // 1/sqrt(8)

    // ---- stage W (640 float4) + u (64 float4): one vmcnt drain ----
    for (int g = t; g < WCH * 32; g += 256) {
        const int c = g >> 5, w = g & 31;
        const int nn = c / ND, d = c - nn * ND;
        reinterpret_cast<float4*>(Wl)[g] =
            *reinterpret_cast<const float4*>(
                W + ((size_t)d * NN + (n0 + nn)) * (DD * DP) + w * 4);
    }
    if (t < BN * NCH * 2) {
        const int b = t >> 2, r = t & 3, nn = r >> 1, half = r & 1;
        reinterpret_cast<float4*>(ul)[t] =
            *reinterpret_cast<const float4*>(
                u + ((size_t)b * NN + (n0 + nn)) * DP + half * 4);
    }
    __syncthreads();

    const int j = t & 15, b = t >> 4;

    // ---- phase A: votes -> registers; partial T -> Tp ----
    float uh[NCH][ND];                   // kept live across grid syncs
    float Tacc[ND];
#pragma unroll
    for (int d = 0; d < ND; ++d) Tacc[d] = 0.f;
#pragma unroll
    for (int nn = 0; nn < NCH; ++nn) {
        const float4 u0 = reinterpret_cast<const float4*>(ul)[b * 4 + nn * 2];
        const float4 u1 = reinterpret_cast<const float4*>(ul)[b * 4 + nn * 2 + 1];
#pragma unroll
        for (int d = 0; d < ND; ++d) {
            const float4* wp =
                reinterpret_cast<const float4*>(Wl) + (nn * ND + d) * 32 + j * 2;
            const float4 w0 = wp[0], w1 = wp[1];
            const float s =
                  w0.x * u0.x + w0.y * u0.y + w0.z * u0.z + w0.w * u0.w
                + w1.x * u1.x + w1.y * u1.y + w1.z * u1.z + w1.w * u1.w;
            uh[nn][d] = s;
            Tacc[d] += s;
        }
    }
    {
        float* dst = Tp + (size_t)blk * CELLS;
#pragma unroll
        for (int d = 0; d < ND; ++d) dst[d * 256 + t] = Tacc[d];
    }

    __threadfence();                     // device-scope release of Tp
    grid.sync();

    // ---- phase R1: blocks 0..159 reduce Tp[576][2560] -> T[2560] ----
    if (blk < RBLK) {
        const int cell = blk * RL + (t & 15);
        const int cc = t >> 4;
        float v[RK];
#pragma unroll
        for (int k = 0; k < RK; ++k)
            v[k] = Tp[(size_t)(cc + RL * k) * CELLS + cell];
        float s = 0.f;
#pragma unroll
        for (int k = 0; k < RK; ++k) s += v[k];
        red[t] = s;
        __syncthreads();
        if (t < RL) {
            float acc = 0.f;
#pragma unroll
            for (int g = 0; g < RL; ++g) acc += red[t + RL * g];
            T[blk * RL + t] = acc;
        }
    }

    __threadfence();                     // release T
    grid.sync();

    // ---- phase B: scores -> softmax_d -> partial S (reuses uh) ----
    float Treg[ND];
#pragma unroll
    for (int q = 0; q < ND; ++q) Treg[q] = T[q * 256 + t];   // coalesced per q

    float Sacc[ND];
#pragma unroll
    for (int q = 0; q < ND; ++q) Sacc[q] = 0.f;

#pragma unroll
    for (int nn = 0; nn < NCH; ++nn) {
        const int n = n0 + nn;
        float a[ND];
#pragma unroll
        for (int q = 0; q < ND; ++q) {
            float v = Treg[q] * uh[nn][q];       // butterfly over 16 j-lanes
            v += __shfl_xor(v, 8, 16);
            v += __shfl_xor(v, 4, 16);
            v += __shfl_xor(v, 2, 16);
            v += __shfl_xor(v, 1, 16);
            a[q] = v * RS8;
        }
        float m = a[0];
#pragma unroll
        for (int q = 1; q < ND; ++q) m = fmaxf(m, a[q]);
        float e[ND], se = 0.f;
#pragma unroll
        for (int q = 0; q < ND; ++q) { e[q] = expf(a[q] - m); se += e[q]; }
        const float inv_se = 1.f / se;
#pragma unroll
        for (int q = 0; q < ND; ++q)
            Sacc[q] += (Bp[q * NN + n] + e[q] * inv_se) * uh[nn][q];
    }
    {
        float* dst = Sp + (size_t)blk * CELLS;
#pragma unroll
        for (int q = 0; q < ND; ++q) dst[q * 256 + t] = Sacc[q];
    }

    __threadfence();                     // release Sp
    grid.sync();

    // ---- phase R2: blocks 0..159 reduce Sp + fused squash -> out ----
    if (blk < RBLK) {
        const int q = blk >> 4, bb = blk & 15;
        const int jj = t & 15, cc = t >> 4;
        const int cell = q * 256 + bb * 16 + jj;
        float v[RK];
#pragma unroll
        for (int k = 0; k < RK; ++k)
            v[k] = Sp[(size_t)(cc + RL * k) * CELLS + cell];
        float s = 0.f;
#pragma unroll
        for (int k = 0; k < RK; ++k) s += v[k];
        red[t] = s;
        __syncthreads();
        if (t < RL) {                    // t = j
            float Sv = 0.f;
#pragma unroll
            for (int g = 0; g < RL; ++g) Sv += red[t + RL * g];
            float n2 = Sv * Sv;
#pragma unroll
            for (int off = 8; off >= 1; off >>= 1) n2 += __shfl_xor(n2, off, 16);
            const float nrm = sqrtf(n2);
            const float coef = 1.f - 1.f / (expf(nrm) + 1e-7f);
            out[((size_t)bb * ND + q) * DD + t] = Sv * (coef / (nrm + 1e-7f));
        }
    }
}

// ================== fallback: proven 4-kernel path ==================
__global__ __launch_bounds__(256) void caps_T(
    const float* __restrict__ u, const float* __restrict__ W,
    float* __restrict__ Tp)
{
    __shared__ float Wl[WCH * 128];
    __shared__ float ul[BN * NCH * DP];
    const int t = threadIdx.x;
    const int n0 = blockIdx.x * NCH;

    for (int g = t; g < WCH * 32; g += 256) {
        const int c = g >> 5, w = g & 31;
        const int nn = c / ND, d = c - nn * ND;
        reinterpret_cast<float4*>(Wl)[g] =
            *reinterpret_cast<const float4*>(
                W + ((size_t)d * NN + (n0 + nn)) * (DD * DP) + w * 4);
    }
    if (t < BN * NCH * 2) {
        const int b = t >> 2, r = t & 3, nn = r >> 1, half = r & 1;
        reinterpret_cast<float4*>(ul)[t] =
            *reinterpret_cast<const float4*>(
                u + ((size_t)b * NN + (n0 + nn)) * DP + half * 4);
    }
    __syncthreads();

    const int j = t & 15, b = t >> 4;
    float Tacc[ND];
#pragma unroll
    for (int d = 0; d < ND; ++d) Tacc[d] = 0.f;
#pragma unroll
    for (int nn = 0; nn < NCH; ++nn) {
        const float4 u0 = reinterpret_cast<const float4*>(ul)[b * 4 + nn * 2];
        const float4 u1 = reinterpret_cast<const float4*>(ul)[b * 4 + nn * 2 + 1];
#pragma unroll
        for (int d = 0; d < ND; ++d) {
            const float4* wp =
                reinterpret_cast<const float4*>(Wl) + (nn * ND + d) * 32 + j * 2;
            const float4 w0 = wp[0], w1 = wp[1];
            Tacc[d] += w0.x * u0.x + w0.y * u0.y + w0.z * u0.z + w0.w * u0.w
                     + w1.x * u1.x + w1.y * u1.y + w1.z * u1.z + w1.w * u1.w;
        }
    }
    float* dst = Tp + (size_t)blockIdx.x * CELLS;
#pragma unroll
    for (int d = 0; d < ND; ++d) dst[d * 256 + t] = Tacc[d];
}

__global__ __launch_bounds__(256) void reduce_T(
    const float* __restrict__ Tp, float* __restrict__ T)
{
    __shared__ float red[256];
    const int t = threadIdx.x;
    const int cell = blockIdx.x * RL + (t & 15);
    const int cc = t >> 4;
    float v[RK];
#pragma unroll
    for (int k = 0; k < RK; ++k)
        v[k] = Tp[(size_t)(cc + RL * k) * CELLS + cell];
    float s = 0.f;
#pragma unroll
    for (int k = 0; k < RK; ++k) s += v[k];
    red[t] = s;
    __syncthreads();
    if (t < RL) {
        float acc = 0.f;
#pragma unroll
        for (int g = 0; g < RL; ++g) acc += red[t + RL * g];
        T[blockIdx.x * RL + t] = acc;
    }
}

__global__ __launch_bounds__(256) void caps_S(
    const float* __restrict__ u, const float* __restrict__ W,
    const float* __restrict__ Bp, const float* __restrict__ T,
    float* __restrict__ Sp)
{
    __shared__ float Wl[WCH * 128];
    __shared__ float ul[BN * NCH * DP];
    __shared__ float Tl[CELLS];
    const int t = threadIdx.x;
    const int n0 = blockIdx.x * NCH;
    constexpr float RS8 = 0.35355339059327373f;

    for (int g = t; g < WCH * 32; g += 256) {
        const int c = g >> 5, w = g & 31;
        const int nn = c / ND, d = c - nn * ND;
        reinterpret_cast<float4*>(Wl)[g] =
            *reinterpret_cast<const float4*>(
                W + ((size_t)d * NN + (n0 + nn)) * (DD * DP) + w * 4);
    }
    for (int g = t; g < CELLS / 4; g += 256)
        reinterpret_cast<float4*>(Tl)[g] = reinterpret_cast<const float4*>(T)[g];
    if (t < BN * NCH * 2) {
        const int b = t >> 2, r = t & 3, nn = r >> 1, half = r & 1;
        reinterpret_cast<float4*>(ul)[t] =
            *reinterpret_cast<const float4*>(
                u + ((size_t)b * NN + (n0 + nn)) * DP + half * 4);
    }
    __syncthreads();

    const int j = t & 15, b = t >> 4;
    float Treg[ND];
#pragma unroll
    for (int q = 0; q < ND; ++q) Treg[q] = Tl[q * 256 + t];

    float Sacc[ND];
#pragma unroll
    for (int q = 0; q < ND; ++q) Sacc[q] = 0.f;

#pragma unroll
    for (int nn = 0; nn < NCH; ++nn) {
        const int n = n0 + nn;
        const float4 u0 = reinterpret_cast<const float4*>(ul)[b * 4 + nn * 2];
        const float4 u1 = reinterpret_cast<const float4*>(ul)[b * 4 + nn * 2 + 1];
        float uh[ND], a[ND];
#pragma unroll
        for (int q = 0; q < ND; ++q) {
            const float4* wp =
                reinterpret_cast<const float4*>(Wl) + (nn * ND + q) * 32 + j * 2;
            const float4 w0 = wp[0], w1 = wp[1];
            const float s =
                  w0.x * u0.x + w0.y * u0.y + w0.z * u0.z + w0.w * u0.w
                + w1.x * u1.x + w1.y * u1.y + w1.z * u1.z + w1.w * u1.w;
            uh[q] = s;
            float v = Treg[q] * s;
            v += __shfl_xor(v, 8, 16);
            v += __shfl_xor(v, 4, 16);
            v += __shfl_xor(v, 2, 16);
            v += __shfl_xor(v, 1, 16);
            a[q] = v * RS8;
        }
        float m = a[0];
#pragma unroll
        for (int q = 1; q < ND; ++q) m = fmaxf(m, a[q]);
        float e[ND], se = 0.f;
#pragma unroll
        for (int q = 0; q < ND; ++q) { e[q] = expf(a[q] - m); se += e[q]; }
        const float inv_se = 1.f / se;
#pragma unroll
        for (int q = 0; q < ND; ++q)
            Sacc[q] += (Bp[q * NN + n] + e[q] * inv_se) * uh[q];
    }
    float* dst = Sp + (size_t)blockIdx.x * CELLS;
#pragma unroll
    for (int q = 0; q < ND; ++q) dst[q * 256 + t] = Sacc[q];
}

__global__ __launch_bounds__(256) void reduce_S_out(
    const float* __restrict__ Sp, float* __restrict__ out)
{
    __shared__ float red[256];
    const int q = blockIdx.x >> 4, b = blockIdx.x & 15;
    const int t = threadIdx.x, j = t & 15, cc = t >> 4;
    const int cell = q * 256 + b * 16 + j;
    float v[RK];
#pragma unroll
    for (int k = 0; k < RK; ++k)
        v[k] = Sp[(size_t)(cc + RL * k) * CELLS + cell];
    float s = 0.f;
#pragma unroll
    for (int k = 0; k < RK; ++k) s += v[k];
    red[t] = s;
    __syncthreads();
    if (t < RL) {
        float Sv = 0.f;
#pragma unroll
        for (int g = 0; g < RL; ++g) Sv += red[t + RL * g];
        float n2 = Sv * Sv;
#pragma unroll
        for (int off = 8; off >= 1; off >>= 1) n2 += __shfl_xor(n2, off, 16);
        const float nrm = sqrtf(n2);
        const float coef = 1.f - 1.f / (expf(nrm) + 1e-7f);
        out[((size_t)b * ND + q) * DD + t] = Sv * (coef / (nrm + 1e-7f));
    }
}

extern "C" void kernel_launch(void* const* d_in, const int* in_sizes, int n_in,
                              void* d_out, int out_size, void* d_ws, size_t ws_size,
                              hipStream_t stream) {
    const float* u  = nullptr;   // 147456
    const float* W  = nullptr;   // 1474560
    const float* Bp = nullptr;   // 11520
    for (int i = 0; i < n_in; ++i) {
        const int s = in_sizes[i];
        if (s == BN * NN * DP)            u  = (const float*)d_in[i];
        else if (s == ND * NN * DD * DP)  W  = (const float*)d_in[i];
        else if (s == ND * NN)            Bp = (const float*)d_in[i];
    }
    float* out = (float*)d_out;
    float* Tp = (float*)d_ws;                     // 576*2560 fp32 = 5.9 MB
    float* T  = Tp + (size_t)NBLK * CELLS;        // 2560 fp32
    float* Sp = T + CELLS;                        // 576*2560 fp32 = 5.9 MB
    // every ws word is written before read -> poison harmless; no memset

    void* args[] = {(void*)&u, (void*)&W, (void*)&Bp,
                    (void*)&Tp, (void*)&T, (void*)&Sp, (void*)&out};
    hipError_t err = hipLaunchCooperativeKernel(
        (void*)caps_fused, dim3(NBLK), dim3(256), args, 0, stream);
    if (err != hipSuccess) {
        // fallback: proven 4-kernel pipeline (bitwise-identical output)
        caps_T      <<<dim3(NBLK), 256, 0, stream>>>(u, W, Tp);
        reduce_T    <<<dim3(CELLS / RL), 256, 0, stream>>>(Tp, T);
        caps_S      <<<dim3(NBLK), 256, 0, stream>>>(u, W, Bp, T, Sp);
        reduce_S_out<<<dim3(ND * BN), 256, 0, stream>>>(Sp, out);
    }
}

// Round 3
// 139.875 us; speedup vs baseline: 2.9731x; 2.9731x over previous
//
#include <hip/hip_runtime.h>

// DigitCaps, fp32 in / fp32 out:
//   u [16,1152,8], W [10,1152,16,8], Bp [10,1,1152], out [16,10,16]
// Exact algebra: A_sum[b,d,m] = dot(T[b,d,:], U_hat[b,d,m,:])/sqrt8,
//   T = sum_n U_hat;  C = softmax_d;  S = sum_n (Bp+C)*U_hat;  squash(S).
// R16: single cooperative kernel with HAND-ROLLED flag barriers.
// R15 post-mortem: cg::grid.sync() costs ~115us/sync on ROCm (VALUBusy
// 0.95%, 358us kernel for ~15us of work); but it PASSED -> threadfence +
// device-scope sync across XCDs is sound. Replace cg with release/acquire
// flag array (~2-3us/barrier), 72 blocks (NCH=16) so each block re-reduces
// Tp itself after barrier 1 (53MB L3 traffic, ~3us) -> only 2 barriers.
// W staged ONCE (80KB LDS), phase B recomputes votes from LDS.
// Fresh magics per host call: stale flags can only release early (rocprof
// replay w/o re-poison), never deadlock.
constexpr int BN = 16, NN = 1152, DP = 8, ND = 10, DD = 16;
constexpr int NCH = 16;                  // n's per block
constexpr int NBLK = NN / NCH;           // 72 blocks
constexpr int CELLS = BN * ND * DD;      // 2560; cell = d*256 + b*16 + j
constexpr int WCH = NCH * ND;            // 160 staged W chunks (512 B each)
constexpr int RGB = (160 + 2) / 3;       // 54 blocks active in final reduce

__device__ __forceinline__ void flag_barrier(unsigned* flags, unsigned magic)
{
    __syncthreads();
    __threadfence();                     // agent-scope release of prior writes
    if (threadIdx.x == 0)
        __hip_atomic_store(&flags[blockIdx.x], magic, __ATOMIC_RELEASE,
                           __HIP_MEMORY_SCOPE_AGENT);
    if (threadIdx.x < NBLK) {            // one flag per poller thread
        while (__hip_atomic_load(&flags[threadIdx.x], __ATOMIC_ACQUIRE,
                                 __HIP_MEMORY_SCOPE_AGENT) != magic)
            __builtin_amdgcn_s_sleep(1);
    }
    __syncthreads();                     // pollers' acquire orders the block
}

// ================== fused kernel: A -> bar -> (R1+B) -> bar -> R2 ==========
__global__ __launch_bounds__(256) void caps_fused(
    const float* __restrict__ u, const float* __restrict__ W,
    const float* __restrict__ Bp, float* __restrict__ Tp,
    float* __restrict__ Sp, unsigned* __restrict__ fl1,
    unsigned* __restrict__ fl2, float* __restrict__ out,
    unsigned m1, unsigned m2)
{
    __shared__ float Wl[WCH * 128];      // 80 KB; persists both phases
    __shared__ float ul[BN * NCH * DP];  // 8 KB
    const int t = threadIdx.x, blk = blockIdx.x;
    const int n0 = blk * NCH;
    constexpr float RS8 = 0.35355339059327373f;    // 1/sqrt(8)
    float4* Wl4 = reinterpret_cast<float4*>(Wl);
    float4* ul4 = reinterpret_cast<float4*>(ul);

    // ---- stage W: 5120 float4, coalesced; half-split layout so compute's
    // ds_read_b128 is 2-way bank aliasing (free) instead of 4-way ----
    for (int g = t; g < WCH * 32; g += 256) {
        const int c = g >> 5, w = g & 31;          // chunk, float4 slot
        const int nn = c / ND, d = c - nn * ND;
        const int jj = w >> 1, half = w & 1;       // slot -> (j, half)
        Wl4[c * 32 + half * 16 + jj] =
            *reinterpret_cast<const float4*>(
                W + ((size_t)d * NN + (n0 + nn)) * (DD * DP) + w * 4);
    }
    // ---- stage u: 512 float4 ----
    for (int g = t; g < BN * NCH * DP / 4; g += 256) {
        const int b = g >> 5, r = g & 31;          // r = nn*2 + half
        ul4[g] = *reinterpret_cast<const float4*>(
            u + ((size_t)b * NN + (n0 + (r >> 1))) * DP + (r & 1) * 4);
    }
    __syncthreads();

    const int j = t & 15, b = t >> 4;

    // ---- phase A: partial T over this block's 16 n's ----
    float Tacc[ND];
#pragma unroll
    for (int d = 0; d < ND; ++d) Tacc[d] = 0.f;
    for (int nn = 0; nn < NCH; ++nn) {
        const float4 u0 = ul4[(b * NCH + nn) * 2];
        const float4 u1 = ul4[(b * NCH + nn) * 2 + 1];
#pragma unroll
        for (int d = 0; d < ND; ++d) {
            const float4 w0 = Wl4[(nn * ND + d) * 32 + j];
            const float4 w1 = Wl4[(nn * ND + d) * 32 + 16 + j];
            Tacc[d] += w0.x * u0.x + w0.y * u0.y + w0.z * u0.z + w0.w * u0.w
                     + w1.x * u1.x + w1.y * u1.y + w1.z * u1.z + w1.w * u1.w;
        }
    }
    {
        float* dst = Tp + (size_t)blk * CELLS;
#pragma unroll
        for (int d = 0; d < ND; ++d) dst[d * 256 + t] = Tacc[d];
    }

    flag_barrier(fl1, m1);

    // ---- R1 (distributed): every block reduces Tp -> its own Treg ----
    float Treg[ND];
#pragma unroll
    for (int q = 0; q < ND; ++q) Treg[q] = 0.f;
    for (int k = 0; k < NBLK; ++k) {
        const float* row = Tp + (size_t)k * CELLS + t;
#pragma unroll
        for (int q = 0; q < ND; ++q) Treg[q] += row[q * 256];
    }

    // ---- phase B: recompute votes from LDS, softmax_d, partial S ----
    float Sacc[ND];
#pragma unroll
    for (int q = 0; q < ND; ++q) Sacc[q] = 0.f;
    for (int nn = 0; nn < NCH; ++nn) {
        const int n = n0 + nn;
        const float4 u0 = ul4[(b * NCH + nn) * 2];
        const float4 u1 = ul4[(b * NCH + nn) * 2 + 1];
        float uh[ND], a[ND];
#pragma unroll
        for (int q = 0; q < ND; ++q) {
            const float4 w0 = Wl4[(nn * ND + q) * 32 + j];
            const float4 w1 = Wl4[(nn * ND + q) * 32 + 16 + j];
            const float s =
                  w0.x * u0.x + w0.y * u0.y + w0.z * u0.z + w0.w * u0.w
                + w1.x * u1.x + w1.y * u1.y + w1.z * u1.z + w1.w * u1.w;
            uh[q] = s;
            float v = Treg[q] * s;                 // butterfly over 16 j-lanes
            v += __shfl_xor(v, 8, 16);
            v += __shfl_xor(v, 4, 16);
            v += __shfl_xor(v, 2, 16);
            v += __shfl_xor(v, 1, 16);
            a[q] = v * RS8;
        }
        float m = a[0];
#pragma unroll
        for (int q = 1; q < ND; ++q) m = fmaxf(m, a[q]);
        float e[ND], se = 0.f;
#pragma unroll
        for (int q = 0; q < ND; ++q) { e[q] = expf(a[q] - m); se += e[q]; }
        const float inv_se = 1.f / se;
#pragma unroll
        for (int q = 0; q < ND; ++q)
            Sacc[q] += (Bp[q * NN + n] + e[q] * inv_se) * uh[q];
    }
    {
        float* dst = Sp + (size_t)blk * CELLS;
#pragma unroll
        for (int q = 0; q < ND; ++q) dst[q * 256 + t] = Sacc[q];
    }

    flag_barrier(fl2, m2);

    // ---- R2: blocks 0..53, 3 (b,q) groups each; reduce + squash -> out ----
    if (blk < RGB) {
        const int sl = t >> 4, jj = t & 15;
        const int g = blk * 3 + sl;                // g = b*10 + q
        if (sl < 3 && g < BN * ND) {
            const int bb = g / ND, qq = g - bb * ND;
            const float* col = Sp + qq * 256 + bb * 16 + jj;
            float Sv = 0.f;
            for (int k = 0; k < NBLK; ++k) Sv += col[(size_t)k * CELLS];
            float n2 = Sv * Sv;
#pragma unroll
            for (int off = 8; off >= 1; off >>= 1) n2 += __shfl_xor(n2, off, 16);
            const float nrm = sqrtf(n2);
            const float coef = 1.f - 1.f / (expf(nrm) + 1e-7f);
            out[(size_t)g * DD + jj] = Sv * (coef / (nrm + 1e-7f));
        }
    }
}

// ================== fallback: proven 4-kernel path (R13) ==================
constexpr int FNCH = 2, FNBLK = NN / FNCH, FRL = 16, FRK = FNBLK / FRL;
constexpr int FWCH = FNCH * ND;

__global__ __launch_bounds__(256) void caps_T(
    const float* __restrict__ u, const float* __restrict__ W,
    float* __restrict__ Tp)
{
    __shared__ float Wl[FWCH * 128];
    __shared__ float ul[BN * FNCH * DP];
    const int t = threadIdx.x;
    const int n0 = blockIdx.x * FNCH;

    for (int g = t; g < FWCH * 32; g += 256) {
        const int c = g >> 5, w = g & 31;
        const int nn = c / ND, d = c - nn * ND;
        reinterpret_cast<float4*>(Wl)[g] =
            *reinterpret_cast<const float4*>(
                W + ((size_t)d * NN + (n0 + nn)) * (DD * DP) + w * 4);
    }
    if (t < BN * FNCH * 2) {
        const int b = t >> 2, r = t & 3, nn = r >> 1, half = r & 1;
        reinterpret_cast<float4*>(ul)[t] =
            *reinterpret_cast<const float4*>(
                u + ((size_t)b * NN + (n0 + nn)) * DP + half * 4);
    }
    __syncthreads();

    const int j = t & 15, b = t >> 4;
    float Tacc[ND];
#pragma unroll
    for (int d = 0; d < ND; ++d) Tacc[d] = 0.f;
#pragma unroll
    for (int nn = 0; nn < FNCH; ++nn) {
        const float4 u0 = reinterpret_cast<const float4*>(ul)[b * 4 + nn * 2];
        const float4 u1 = reinterpret_cast<const float4*>(ul)[b * 4 + nn * 2 + 1];
#pragma unroll
        for (int d = 0; d < ND; ++d) {
            const float4* wp =
                reinterpret_cast<const float4*>(Wl) + (nn * ND + d) * 32 + j * 2;
            const float4 w0 = wp[0], w1 = wp[1];
            Tacc[d] += w0.x * u0.x + w0.y * u0.y + w0.z * u0.z + w0.w * u0.w
                     + w1.x * u1.x + w1.y * u1.y + w1.z * u1.z + w1.w * u1.w;
        }
    }
    float* dst = Tp + (size_t)blockIdx.x * CELLS;
#pragma unroll
    for (int d = 0; d < ND; ++d) dst[d * 256 + t] = Tacc[d];
}

__global__ __launch_bounds__(256) void reduce_T(
    const float* __restrict__ Tp, float* __restrict__ T)
{
    __shared__ float red[256];
    const int t = threadIdx.x;
    const int cell = blockIdx.x * FRL + (t & 15);
    const int cc = t >> 4;
    float v[FRK];
#pragma unroll
    for (int k = 0; k < FRK; ++k)
        v[k] = Tp[(size_t)(cc + FRL * k) * CELLS + cell];
    float s = 0.f;
#pragma unroll
    for (int k = 0; k < FRK; ++k) s += v[k];
    red[t] = s;
    __syncthreads();
    if (t < FRL) {
        float acc = 0.f;
#pragma unroll
        for (int g = 0; g < FRL; ++g) acc += red[t + FRL * g];
        T[blockIdx.x * FRL + t] = acc;
    }
}

__global__ __launch_bounds__(256) void caps_S(
    const float* __restrict__ u, const float* __restrict__ W,
    const float* __restrict__ Bp, const float* __restrict__ T,
    float* __restrict__ Sp)
{
    __shared__ float Wl[FWCH * 128];
    __shared__ float ul[BN * FNCH * DP];
    __shared__ float Tl[CELLS];
    const int t = threadIdx.x;
    const int n0 = blockIdx.x * FNCH;
    constexpr float RS8 = 0.35355339059327373f;

    for (int g = t; g < FWCH * 32; g += 256) {
        const int c = g >> 5, w = g & 31;
        const int nn = c / ND, d = c - nn * ND;
        reinterpret_cast<float4*>(Wl)[g] =
            *reinterpret_cast<const float4*>(
                W + ((size_t)d * NN + (n0 + nn)) * (DD * DP) + w * 4);
    }
    for (int g = t; g < CELLS / 4; g += 256)
        reinterpret_cast<float4*>(Tl)[g] = reinterpret_cast<const float4*>(T)[g];
    if (t < BN * FNCH * 2) {
        const int b = t >> 2, r = t & 3, nn = r >> 1, half = r & 1;
        reinterpret_cast<float4*>(ul)[t] =
            *reinterpret_cast<const float4*>(
                u + ((size_t)b * NN + (n0 + nn)) * DP + half * 4);
    }
    __syncthreads();

    const int j = t & 15, b = t >> 4;
    float Treg[ND];
#pragma unroll
    for (int q = 0; q < ND; ++q) Treg[q] = Tl[q * 256 + t];

    float Sacc[ND];
#pragma unroll
    for (int q = 0; q < ND; ++q) Sacc[q] = 0.f;

#pragma unroll
    for (int nn = 0; nn < FNCH; ++nn) {
        const int n = n0 + nn;
        const float4 u0 = reinterpret_cast<const float4*>(ul)[b * 4 + nn * 2];
        const float4 u1 = reinterpret_cast<const float4*>(ul)[b * 4 + nn * 2 + 1];
        float uh[ND], a[ND];
#pragma unroll
        for (int q = 0; q < ND; ++q) {
            const float4* wp =
                reinterpret_cast<const float4*>(Wl) + (nn * ND + q) * 32 + j * 2;
            const float4 w0 = wp[0], w1 = wp[1];
            const float s =
                  w0.x * u0.x + w0.y * u0.y + w0.z * u0.z + w0.w * u0.w
                + w1.x * u1.x + w1.y * u1.y + w1.z * u1.z + w1.w * u1.w;
            uh[q] = s;
            float v = Treg[q] * s;
            v += __shfl_xor(v, 8, 16);
            v += __shfl_xor(v, 4, 16);
            v += __shfl_xor(v, 2, 16);
            v += __shfl_xor(v, 1, 16);
            a[q] = v * RS8;
        }
        float m = a[0];
#pragma unroll
        for (int q = 1; q < ND; ++q) m = fmaxf(m, a[q]);
        float e[ND], se = 0.f;
#pragma unroll
        for (int q = 0; q < ND; ++q) { e[q] = expf(a[q] - m); se += e[q]; }
        const float inv_se = 1.f / se;
#pragma unroll
        for (int q = 0; q < ND; ++q)
            Sacc[q] += (Bp[q * NN + n] + e[q] * inv_se) * uh[q];
    }
    float* dst = Sp + (size_t)blockIdx.x * CELLS;
#pragma unroll
    for (int q = 0; q < ND; ++q) dst[q * 256 + t] = Sacc[q];
}

__global__ __launch_bounds__(256) void reduce_S_out(
    const float* __restrict__ Sp, float* __restrict__ out)
{
    __shared__ float red[256];
    const int q = blockIdx.x >> 4, b = blockIdx.x & 15;
    const int t = threadIdx.x, j = t & 15, cc = t >> 4;
    const int cell = q * 256 + b * 16 + j;
    float v[FRK];
#pragma unroll
    for (int k = 0; k < FRK; ++k)
        v[k] = Sp[(size_t)(cc + FRL * k) * CELLS + cell];
    float s = 0.f;
#pragma unroll
    for (int k = 0; k < FRK; ++k) s += v[k];
    red[t] = s;
    __syncthreads();
    if (t < FRL) {
        float Sv = 0.f;
#pragma unroll
        for (int g = 0; g < FRL; ++g) Sv += red[t + FRL * g];
        float n2 = Sv * Sv;
#pragma unroll
        for (int off = 8; off >= 1; off >>= 1) n2 += __shfl_xor(n2, off, 16);
        const float nrm = sqrtf(n2);
        const float coef = 1.f - 1.f / (expf(nrm) + 1e-7f);
        out[((size_t)b * ND + q) * DD + t] = Sv * (coef / (nrm + 1e-7f));
    }
}

extern "C" void kernel_launch(void* const* d_in, const int* in_sizes, int n_in,
                              void* d_out, int out_size, void* d_ws, size_t ws_size,
                              hipStream_t stream) {
    const float* u  = nullptr;   // 147456
    const float* W  = nullptr;   // 1474560
    const float* Bp = nullptr;   // 11520
    for (int i = 0; i < n_in; ++i) {
        const int s = in_sizes[i];
        if (s == BN * NN * DP)            u  = (const float*)d_in[i];
        else if (s == ND * NN * DD * DP)  W  = (const float*)d_in[i];
        else if (s == ND * NN)            Bp = (const float*)d_in[i];
    }
    float* out = (float*)d_out;
    char*  wsc = (char*)d_ws;
    // fused layout (all written before read each call; flags validated by
    // per-call magic, so stale contents can never deadlock)
    float*    Tp72 = (float*)wsc;                        // 737,280 B
    float*    Sp72 = (float*)(wsc + (1u << 20));         // 737,280 B
    unsigned* fl1  = (unsigned*)(wsc + (2u << 20));
    unsigned* fl2  = (unsigned*)(wsc + (2u << 20) + 4096);
    // fallback layout (disjoint, at 16 MB)
    float* Tp576 = (float*)(wsc + (16u << 20));          // 5.9 MB
    float* T576  = Tp576 + (size_t)FNBLK * CELLS;        // 10 KB
    float* Sp576 = T576 + CELLS;                         // 5.9 MB

    static unsigned salt = 0x12345u;
    salt += 0x9E3779B9u;                 // fresh magics every host call
    unsigned m1 = salt | 1u;
    unsigned m2 = m1 ^ 0x5A5A5A5Au;

    void* args[] = {(void*)&u, (void*)&W, (void*)&Bp, (void*)&Tp72,
                    (void*)&Sp72, (void*)&fl1, (void*)&fl2, (void*)&out,
                    (void*)&m1, (void*)&m2};
    hipError_t err = hipLaunchCooperativeKernel(
        (void*)caps_fused, dim3(NBLK), dim3(256), args, 0, stream);
    if (err != hipSuccess) {
        // fallback: proven 4-kernel pipeline
        caps_T      <<<dim3(FNBLK), 256, 0, stream>>>(u, W, Tp576);
        reduce_T    <<<dim3(CELLS / FRL), 256, 0, stream>>>(Tp576, T576);
        caps_S      <<<dim3(FNBLK), 256, 0, stream>>>(u, W, Bp, T576, Sp576);
        reduce_S_out<<<dim3(ND * BN), 256, 0, stream>>>(Sp576, out);
    }
}